// Round 2
// baseline (45796.500 us; speedup 1.0000x reference)
//
#include <hip/hip_runtime.h>
#include <hip/hip_bf16.h>

// RNN: h_t = tanh(x_t @ Wx + h_{t-1} @ Wh + b), B=32, S=1024, D=H=1024, fp32.
// Phase 1: Xp = x@Wx + b in-place into d_out.
// Phase 2: ONE persistent cooperative kernel runs all 1024 steps.
//   - Wh resident in LDS (64KB col-slice per WG), h staged per step (32KB).
//   - 256 WGs = 4 bgroups x 64 ngroups; per-bgroup counter barrier in d_ws.

#define BB 32
#define SS 1024
#define DD 1024
#define HH 1024
#define NG 64   // n-groups of 16 cols
#define BG 4    // b-groups of 8 batches
#define WGN (NG * BG)

// ---------------- Phase 1: C = A @ W + bias ----------------
__global__ __launch_bounds__(256) void xw_gemm(const float* __restrict__ A,
                                               const float* __restrict__ W,
                                               const float* __restrict__ bias,
                                               float* __restrict__ C) {
    __shared__ float As[8][132];
    __shared__ float Bs[8][132];
    const int tid = threadIdx.x;
    const int n0 = blockIdx.x * 128;
    const int m0 = blockIdx.y * 128;
    const int tx = tid & 15;
    const int ty = tid >> 4;
    const int ar = tid >> 1;
    const int ak = (tid & 1) * 4;
    const int bk = tid >> 5;
    const int bn = (tid & 31) * 4;

    float acc[8][8];
#pragma unroll
    for (int i = 0; i < 8; ++i)
#pragma unroll
        for (int j = 0; j < 8; ++j) acc[i][j] = 0.f;

    for (int k0 = 0; k0 < DD; k0 += 8) {
        float4 av = *(const float4*)(A + (size_t)(m0 + ar) * DD + k0 + ak);
        float4 bv = *(const float4*)(W + (size_t)(k0 + bk) * HH + n0 + bn);
        __syncthreads();
        As[ak + 0][ar] = av.x;
        As[ak + 1][ar] = av.y;
        As[ak + 2][ar] = av.z;
        As[ak + 3][ar] = av.w;
        *(float4*)&Bs[bk][bn] = bv;
        __syncthreads();
#pragma unroll
        for (int k = 0; k < 8; ++k) {
            float4 a0 = *(const float4*)&As[k][ty * 4];
            float4 a1 = *(const float4*)&As[k][64 + ty * 4];
            float4 b0 = *(const float4*)&Bs[k][tx * 4];
            float4 b1 = *(const float4*)&Bs[k][64 + tx * 4];
            float ar_[8] = {a0.x, a0.y, a0.z, a0.w, a1.x, a1.y, a1.z, a1.w};
            float br_[8] = {b0.x, b0.y, b0.z, b0.w, b1.x, b1.y, b1.z, b1.w};
#pragma unroll
            for (int i = 0; i < 8; ++i)
#pragma unroll
                for (int j = 0; j < 8; ++j)
                    acc[i][j] = fmaf(ar_[i], br_[j], acc[i][j]);
        }
    }

    float4 bv0 = *(const float4*)(bias + n0 + tx * 4);
    float4 bv1 = *(const float4*)(bias + n0 + 64 + tx * 4);
#pragma unroll
    for (int i = 0; i < 8; ++i) {
        int m = m0 + ((i < 4) ? (ty * 4 + i) : (64 + ty * 4 + (i - 4)));
        float4 r0 = {acc[i][0] + bv0.x, acc[i][1] + bv0.y,
                     acc[i][2] + bv0.z, acc[i][3] + bv0.w};
        float4 r1 = {acc[i][4] + bv1.x, acc[i][5] + bv1.y,
                     acc[i][6] + bv1.z, acc[i][7] + bv1.w};
        *(float4*)(C + (size_t)m * HH + n0 + tx * 4) = r0;
        *(float4*)(C + (size_t)m * HH + n0 + 64 + tx * 4) = r1;
    }
}

// ---------------- WhT[n][k] = Wh[k][n] ----------------
__global__ __launch_bounds__(256) void transpose_wh(const float* __restrict__ in,
                                                    float* __restrict__ outT) {
    __shared__ float tile[32][33];
    const int tx = threadIdx.x & 31;
    const int ty = threadIdx.x >> 5;
    const int x0 = blockIdx.x * 32;
    const int y0 = blockIdx.y * 32;
    for (int r = ty; r < 32; r += 8)
        tile[r][tx] = in[(size_t)(y0 + r) * HH + x0 + tx];
    __syncthreads();
    for (int r = ty; r < 32; r += 8)
        outT[(size_t)(x0 + r) * HH + y0 + tx] = tile[tx][r];
}

// ---------------- Persistent RNN over all S steps ----------------
// WG(bg,ng): batches b0..b0+7, cols n0..n0+15. Thread tile 8b x 8n x 8k:
//   ns = tid>>7 (col half), kq = tid&127 -> k in [4kq,4kq+4) u [512+4kq, +4).
// All LDS reads linear (consecutive lanes -> consecutive 16B): conflict-free.
__global__ __launch_bounds__(256, 1) void rnn_persist(
    const float* __restrict__ Wh, const float* __restrict__ WhT,
    const float* __restrict__ h0, float* __restrict__ out,
    unsigned int* __restrict__ barrier_cnt) {
    __shared__ float WsT[16][1024];  // 64KB [col][k]
    __shared__ float hs[8][1024];    // 32KB [b][k]
    __shared__ float red[4][64];     // cross-wave partials

    const int tid  = threadIdx.x;
    const int ng   = blockIdx.x & 63;
    const int bg   = blockIdx.x >> 6;
    const int n0   = ng * 16;
    const int b0   = bg * 8;
    const int lane = tid & 63;
    const int wv   = tid >> 6;
    const int ns   = tid >> 7;
    const int kq   = tid & 127;
    unsigned int* cnt = barrier_cnt + bg * 64;  // 256B apart per bgroup

    // --- one-time: load Wh column-slice (transposed) into LDS ---
    {
        const int c   = tid >> 4;
        const int t16 = tid & 15;
        if (WhT) {
            const float* src = WhT + (size_t)(n0 + c) * HH;
#pragma unroll
            for (int j = 0; j < 16; ++j) {
                int k4 = (j * 16 + t16) * 4;
                *(float4*)&WsT[c][k4] = *(const float4*)(src + k4);
            }
        } else {
            for (int j = 0; j < 64; ++j) {
                int k = j * 16 + t16;
                WsT[c][k] = Wh[(size_t)k * HH + n0 + c];
            }
        }
    }

    // epilogue/Xp mapping: thread (tid<128) owns output (eb, ec)
    int eb = 0, ec = 0;
    size_t xp_base = 0;
    if (tid < 128) {
        int l   = tid & 63;
        int idx = (int)(__brev((unsigned)l) >> 26);  // 6-bit bit-reverse
        eb = idx >> 3;
        ec = (tid >> 6) * 8 + (idx & 7);
        xp_base = ((size_t)(b0 + eb) * SS) * HH + (n0 + ec);
    }
    __syncthreads();

    for (int t = 0; t < SS; ++t) {
        // ---- stage h_{t-1} (or h0) into hs; prefetch Xp ----
        if (t == 0) {
#pragma unroll
            for (int j = 0; j < 8; ++j) {
                int f4 = tid + 256 * j;
                int r = f4 >> 8, c4 = (f4 & 255) * 4;
                *(float4*)&hs[r][c4] = *(const float4*)(h0 + c4);
            }
        } else {
#pragma unroll
            for (int j = 0; j < 8; ++j) {
                int f4 = tid + 256 * j;
                int r = f4 >> 8, c4 = (f4 & 255) * 4;
                *(float4*)&hs[r][c4] =
                    *(const float4*)(out + ((size_t)(b0 + r) * SS + (t - 1)) * HH + c4);
            }
        }
        float xp = 0.f;
        if (tid < 128) xp = out[xp_base + (size_t)t * HH];
        __syncthreads();

        // ---- 512 FMA per thread ----
        float a[64];
#pragma unroll
        for (int i = 0; i < 64; ++i) a[i] = 0.f;
#pragma unroll
        for (int half = 0; half < 2; ++half) {
            const int kb = half * 512 + kq * 4;
            float4 w[8], h[8];
#pragma unroll
            for (int c = 0; c < 8; ++c) w[c] = *(const float4*)&WsT[ns * 8 + c][kb];
#pragma unroll
            for (int b = 0; b < 8; ++b) h[b] = *(const float4*)&hs[b][kb];
#pragma unroll
            for (int b = 0; b < 8; ++b)
#pragma unroll
                for (int c = 0; c < 8; ++c)
                    a[b * 8 + c] += h[b].x * w[c].x + h[b].y * w[c].y +
                                    h[b].z * w[c].z + h[b].w * w[c].w;
        }

        // ---- folding in-wave reduce over kq (outputs land at lane=brev(idx)) ----
        int s = 64;
#pragma unroll
        for (int m = 1; m <= 32; m <<= 1) {
            const int hs_ = s >> 1;
            const bool hi = (lane & m) != 0;
#pragma unroll
            for (int i = 0; i < hs_; ++i) {
                float lo = a[i], hg = a[i + hs_];
                a[i]       = hi ? hg : lo;
                a[i + hs_] = hi ? lo : hg;
            }
#pragma unroll
            for (int i = 0; i < hs_; ++i) a[i] += __shfl_xor(a[i + hs_], m, 64);
            s = hs_;
        }

        red[wv][lane] = a[0];
        __syncthreads();

        if (tid < 128) {
            const int l = tid & 63;
            const int nss = tid >> 6;
            float v = red[nss * 2][l] + red[nss * 2 + 1][l];
            out[xp_base + (size_t)t * HH] = tanhf(v + xp);
        }

        // ---- per-bgroup barrier (release h_t, acquire others') ----
        __threadfence();
        __syncthreads();
        if (tid == 0) {
            __hip_atomic_fetch_add(cnt, 1u, __ATOMIC_RELEASE, __HIP_MEMORY_SCOPE_AGENT);
            const unsigned target = (unsigned)(t + 1) * NG;
            while (__hip_atomic_load(cnt, __ATOMIC_ACQUIRE, __HIP_MEMORY_SCOPE_AGENT) < target)
                __builtin_amdgcn_s_sleep(2);
        }
        __syncthreads();
        __threadfence();
    }
}

extern "C" void kernel_launch(void* const* d_in, const int* in_sizes, int n_in,
                              void* d_out, int out_size, void* d_ws, size_t ws_size,
                              hipStream_t stream) {
    const float* x    = (const float*)d_in[0];
    const float* Wx   = (const float*)d_in[1];
    const float* Wh   = (const float*)d_in[2];
    const float* bias = (const float*)d_in[3];
    const float* h0   = (const float*)d_in[4];
    float* out = (float*)d_out;
    float* ws  = (float*)d_ws;

    // barrier counters: 4 x 64 uints at ws[0..255]; reset every launch (replay-safe)
    unsigned int* cnt = (unsigned int*)ws;
    hipMemsetAsync(cnt, 0, 1024, stream);

    // Phase 1: Xp = x@Wx + b -> d_out
    xw_gemm<<<dim3(8, 256), 256, 0, stream>>>(x, Wx, bias, out);

    // WhT in ws if it fits (for coalesced LDS fill); else kernel gathers from Wh
    const float* WhT = nullptr;
    if (ws_size >= (size_t)(1024 + HH * HH) * sizeof(float)) {
        float* whtp = ws + 1024;
        transpose_wh<<<dim3(32, 32), 256, 0, stream>>>(Wh, whtp);
        WhT = whtp;
    }

    // Phase 2: persistent kernel, cooperative for guaranteed co-residency
    void* kargs[] = {(void*)&Wh, (void*)&WhT, (void*)&h0, (void*)&out, (void*)&cnt};
    hipError_t rc = hipLaunchCooperativeKernel((const void*)rnn_persist, dim3(WGN),
                                               dim3(256), kargs, 0, stream);
    if (rc != hipSuccess) {
        // fallback: plain launch (256 WGs = 1/CU; co-resident in practice)
        rnn_persist<<<dim3(WGN), dim3(256), 0, stream>>>(Wh, WhT, h0, out, cnt);
    }
}

// Round 4
// 15669.418 us; speedup vs baseline: 2.9227x; 2.9227x over previous
//
#include <hip/hip_runtime.h>
#include <hip/hip_bf16.h>

// RNN: h_t = tanh(x_t @ Wx + h_{t-1} @ Wh + b), B=32, S=1024, D=H=1024, fp32.
// Phase 1: Xp = x@Wx + b in-place into d_out.
// Phase 2: ONE persistent kernel (Wh in LDS). Cross-WG h exchange via a
//   dedicated ping-pong buffer in d_ws touched ONLY by agent-scope atomics
//   (no plain access -> no stale cached lines), RELEASE flag store per step
//   (ordering data-vs-flag at the coherence point), RELAXED poll (cheap).

#define BB 32
#define SS 1024
#define DD 1024
#define HH 1024
#define NG 64   // n-groups of 16 cols
#define BG 4    // b-groups of 8 batches
#define WGN (NG * BG)

// ---------------- Phase 1: C = A @ W + bias ----------------
__global__ __launch_bounds__(256) void xw_gemm(const float* __restrict__ A,
                                               const float* __restrict__ W,
                                               const float* __restrict__ bias,
                                               float* __restrict__ C) {
    __shared__ float As[8][132];
    __shared__ float Bs[8][132];
    const int tid = threadIdx.x;
    const int n0 = blockIdx.x * 128;
    const int m0 = blockIdx.y * 128;
    const int tx = tid & 15;
    const int ty = tid >> 4;
    const int ar = tid >> 1;
    const int ak = (tid & 1) * 4;
    const int bk = tid >> 5;
    const int bn = (tid & 31) * 4;

    float acc[8][8];
#pragma unroll
    for (int i = 0; i < 8; ++i)
#pragma unroll
        for (int j = 0; j < 8; ++j) acc[i][j] = 0.f;

    for (int k0 = 0; k0 < DD; k0 += 8) {
        float4 av = *(const float4*)(A + (size_t)(m0 + ar) * DD + k0 + ak);
        float4 bv = *(const float4*)(W + (size_t)(k0 + bk) * HH + n0 + bn);
        __syncthreads();
        As[ak + 0][ar] = av.x;
        As[ak + 1][ar] = av.y;
        As[ak + 2][ar] = av.z;
        As[ak + 3][ar] = av.w;
        *(float4*)&Bs[bk][bn] = bv;
        __syncthreads();
#pragma unroll
        for (int k = 0; k < 8; ++k) {
            float4 a0 = *(const float4*)&As[k][ty * 4];
            float4 a1 = *(const float4*)&As[k][64 + ty * 4];
            float4 b0 = *(const float4*)&Bs[k][tx * 4];
            float4 b1 = *(const float4*)&Bs[k][64 + tx * 4];
            float ar_[8] = {a0.x, a0.y, a0.z, a0.w, a1.x, a1.y, a1.z, a1.w};
            float br_[8] = {b0.x, b0.y, b0.z, b0.w, b1.x, b1.y, b1.z, b1.w};
#pragma unroll
            for (int i = 0; i < 8; ++i)
#pragma unroll
                for (int j = 0; j < 8; ++j)
                    acc[i][j] = fmaf(ar_[i], br_[j], acc[i][j]);
        }
    }

    float4 bv0 = *(const float4*)(bias + n0 + tx * 4);
    float4 bv1 = *(const float4*)(bias + n0 + 64 + tx * 4);
#pragma unroll
    for (int i = 0; i < 8; ++i) {
        int m = m0 + ((i < 4) ? (ty * 4 + i) : (64 + ty * 4 + (i - 4)));
        float4 r0 = {acc[i][0] + bv0.x, acc[i][1] + bv0.y,
                     acc[i][2] + bv0.z, acc[i][3] + bv0.w};
        float4 r1 = {acc[i][4] + bv1.x, acc[i][5] + bv1.y,
                     acc[i][6] + bv1.z, acc[i][7] + bv1.w};
        *(float4*)(C + (size_t)m * HH + n0 + tx * 4) = r0;
        *(float4*)(C + (size_t)m * HH + n0 + 64 + tx * 4) = r1;
    }
}

// ---------------- WhT[n][k] = Wh[k][n] ----------------
__global__ __launch_bounds__(256) void transpose_wh(const float* __restrict__ in,
                                                    float* __restrict__ outT) {
    __shared__ float tile[32][33];
    const int tx = threadIdx.x & 31;
    const int ty = threadIdx.x >> 5;
    const int x0 = blockIdx.x * 32;
    const int y0 = blockIdx.y * 32;
    for (int r = ty; r < 32; r += 8)
        tile[r][tx] = in[(size_t)(y0 + r) * HH + x0 + tx];
    __syncthreads();
    for (int r = ty; r < 32; r += 8)
        outT[(size_t)(x0 + r) * HH + y0 + tx] = tile[tx][r];
}

// ---------------- Persistent RNN over all S steps ----------------
__global__ __launch_bounds__(256, 1) void rnn_persist(
    const float* __restrict__ Wh, const float* __restrict__ WhT,
    const float* __restrict__ h0, float* __restrict__ out,
    unsigned int* __restrict__ flags, float* __restrict__ hbuf) {
    __shared__ float WsT[16][1024];  // 64KB [col][k]
    __shared__ float hs[8][1024];    // 32KB [b][k]
    __shared__ float red[4][64];

    const int tid  = threadIdx.x;
    const int ng   = blockIdx.x & 63;
    const int bg   = blockIdx.x >> 6;
    const int n0   = ng * 16;
    const int b0   = bg * 8;
    const int lane = tid & 63;
    const int wv   = tid >> 6;
    const int ns   = tid >> 7;
    const int kq   = tid & 127;
    unsigned int* myflags = flags + bg * 64;

    // --- one-time: Wh column-slice (transposed) into LDS ---
    {
        const int c   = tid >> 4;
        const int t16 = tid & 15;
        if (WhT) {
            const float* src = WhT + (size_t)(n0 + c) * HH;
#pragma unroll
            for (int j = 0; j < 16; ++j) {
                int k4 = (j * 16 + t16) * 4;
                *(float4*)&WsT[c][k4] = *(const float4*)(src + k4);
            }
        } else {
            for (int j = 0; j < 64; ++j) {
                int k = j * 16 + t16;
                WsT[c][k] = Wh[(size_t)k * HH + n0 + c];
            }
        }
    }

    // epilogue mapping: thread (tid<128) owns output (eb, ec)
    size_t xp_base = 0;
    int hb_off = 0;
    if (tid < 128) {
        int l   = tid & 63;
        int idx = (int)(__brev((unsigned)l) >> 26);
        int eb  = idx >> 3;
        int ec  = (tid >> 6) * 8 + (idx & 7);
        xp_base = ((size_t)(b0 + eb) * SS) * HH + (n0 + ec);
        hb_off  = (b0 + eb) * HH + (n0 + ec);
    }
    __syncthreads();

    for (int t = 0; t < SS; ++t) {
        // ---- wait for h_{t-1} then stage it into LDS ----
        if (t == 0) {
#pragma unroll
            for (int j = 0; j < 8; ++j) {
                int f4 = tid + 256 * j;
                int r = f4 >> 8, c4 = (f4 & 255) * 4;
                *(float4*)&hs[r][c4] = *(const float4*)(h0 + c4);
            }
        } else {
            if (wv == 0) {
                const unsigned target = (unsigned)t;
                for (;;) {
                    unsigned v = __hip_atomic_load(&myflags[lane], __ATOMIC_RELAXED,
                                                   __HIP_MEMORY_SCOPE_AGENT);
                    if (__all((int)(v >= target))) break;
                    __builtin_amdgcn_s_sleep(1);
                }
            }
            __syncthreads();
            asm volatile("" ::: "memory");
            // hbuf[(t-1)&1] is touched ONLY via agent-scope atomics (8B each)
            const unsigned long long* hsrc =
                (const unsigned long long*)(hbuf + (size_t)((t - 1) & 1) * BB * HH);
#pragma unroll
            for (int j = 0; j < 16; ++j) {
                int idx = tid + 256 * j;       // 0..4095 over 8 rows x 512 ulls
                int r   = idx >> 9;
                int c2  = idx & 511;
                unsigned long long u = __hip_atomic_load(
                    hsrc + (size_t)(b0 + r) * (HH / 2) + c2,
                    __ATOMIC_RELAXED, __HIP_MEMORY_SCOPE_AGENT);
                *(unsigned long long*)&hs[r][c2 * 2] = u;
            }
        }
        float xp = 0.f;
        if (tid < 128) xp = out[xp_base + (size_t)t * HH];
        __syncthreads();

        // ---- 512 FMA per thread ----
        float a[64];
#pragma unroll
        for (int i = 0; i < 64; ++i) a[i] = 0.f;
#pragma unroll
        for (int half = 0; half < 2; ++half) {
            const int kb = half * 512 + kq * 4;
            float4 w[8], h[8];
#pragma unroll
            for (int c = 0; c < 8; ++c) w[c] = *(const float4*)&WsT[ns * 8 + c][kb];
#pragma unroll
            for (int b = 0; b < 8; ++b) h[b] = *(const float4*)&hs[b][kb];
#pragma unroll
            for (int b = 0; b < 8; ++b)
#pragma unroll
                for (int c = 0; c < 8; ++c)
                    a[b * 8 + c] += h[b].x * w[c].x + h[b].y * w[c].y +
                                    h[b].z * w[c].z + h[b].w * w[c].w;
        }

        // ---- folding in-wave reduce over kq ----
        int s = 64;
#pragma unroll
        for (int m = 1; m <= 32; m <<= 1) {
            const int hs_ = s >> 1;
            const bool hi = (lane & m) != 0;
#pragma unroll
            for (int i = 0; i < hs_; ++i) {
                float lo = a[i], hg = a[i + hs_];
                a[i]       = hi ? hg : lo;
                a[i + hs_] = hi ? lo : hg;
            }
#pragma unroll
            for (int i = 0; i < hs_; ++i) a[i] += __shfl_xor(a[i + hs_], m, 64);
            s = hs_;
        }

        red[wv][lane] = a[0];
        __syncthreads();

        if (tid < 128) {
            const int l = tid & 63;
            const int nss = tid >> 6;
            float v = red[nss * 2][l] + red[nss * 2 + 1][l];
            float hv = tanhf(v + xp);
            out[xp_base + (size_t)t * HH] = hv;          // plain (write-only in-kernel)
            __hip_atomic_store(hbuf + (size_t)(t & 1) * BB * HH + hb_off, hv,
                               __ATOMIC_RELAXED, __HIP_MEMORY_SCOPE_AGENT);
        }

        // ---- release: RELEASE flag store orders h stores before flag at MALL ----
        __syncthreads();
        if (tid == 0)
            __hip_atomic_store(&myflags[ng], (unsigned)(t + 1), __ATOMIC_RELEASE,
                               __HIP_MEMORY_SCOPE_AGENT);
    }
}

// ---------------- fallback path (tiny ws): multi-launch steps ----------------
__global__ __launch_bounds__(256) void h0wh(const float* __restrict__ Wh,
                                            const float* __restrict__ h0,
                                            float* __restrict__ c) {
    const int g = blockIdx.x;
    const int n = threadIdx.x * 4;
    float4 a = {0.f, 0.f, 0.f, 0.f};
    for (int kk = 0; kk < 16; ++kk) {
        int k = g * 16 + kk;
        float hv = h0[k];
        float4 w = *(const float4*)(Wh + (size_t)k * HH + n);
        a.x += hv * w.x; a.y += hv * w.y; a.z += hv * w.z; a.w += hv * w.w;
    }
    atomicAdd(&c[n + 0], a.x);
    atomicAdd(&c[n + 1], a.y);
    atomicAdd(&c[n + 2], a.z);
    atomicAdd(&c[n + 3], a.w);
}

__global__ __launch_bounds__(256) void t0_kernel(float* __restrict__ out,
                                                 const float* __restrict__ c) {
    const int idx = blockIdx.x * 256 + threadIdx.x;
    const int b = idx >> 10;
    const int n = idx & 1023;
    const size_t p = (size_t)b * SS * HH + n;
    out[p] = tanhf(out[p] + c[n]);
}

__global__ __launch_bounds__(256) void rnn_step(const float* __restrict__ Wh,
                                                float* __restrict__ out, int t) {
    __shared__ float hsl[8][1028];
    __shared__ float ps[256];
    const int tid = threadIdx.x;
    const int n0 = blockIdx.x * 16;
    const int b0 = blockIdx.y * 8;
    for (int i = tid; i < 8 * 256; i += 256) {
        int r = i >> 8;
        int c = (i & 255) << 2;
        *(float4*)&hsl[r][c] =
            *(const float4*)(out + ((size_t)(b0 + r) * SS + (t - 1)) * HH + c);
    }
    __syncthreads();
    const int nl = tid & 15;
    const int bl = (tid >> 4) & 7;
    const int half = tid >> 7;
    const int n = n0 + nl;
    float acc = 0.f;
    const float* hrow = &hsl[bl][half * 512];
    const float* wcol = Wh + (size_t)(half * 512) * HH + n;
#pragma unroll 4
    for (int k = 0; k < 512; k += 4) {
        float4 h4 = *(const float4*)(hrow + k);
        acc += h4.x * wcol[(size_t)(k + 0) * HH];
        acc += h4.y * wcol[(size_t)(k + 1) * HH];
        acc += h4.z * wcol[(size_t)(k + 2) * HH];
        acc += h4.w * wcol[(size_t)(k + 3) * HH];
    }
    ps[tid] = acc;
    __syncthreads();
    if (tid < 128) {
        const size_t obase = ((size_t)(b0 + bl) * SS + t) * HH + n;
        out[obase] = tanhf(out[obase] + ps[tid] + ps[tid + 128]);
    }
}

extern "C" void kernel_launch(void* const* d_in, const int* in_sizes, int n_in,
                              void* d_out, int out_size, void* d_ws, size_t ws_size,
                              hipStream_t stream) {
    const float* x    = (const float*)d_in[0];
    const float* Wx   = (const float*)d_in[1];
    const float* Wh   = (const float*)d_in[2];
    const float* bias = (const float*)d_in[3];
    const float* h0   = (const float*)d_in[4];
    float* out = (float*)d_out;
    float* ws  = (float*)d_ws;

    // Phase 1: Xp = x@Wx + b -> d_out
    xw_gemm<<<dim3(8, 256), 256, 0, stream>>>(x, Wx, bias, out);

    // ws layout: [0..255] flags (uint) | [256..] hbuf 2*32*1024 f | WhT 1024*1024 f
    const size_t need_persist = (size_t)(256 + 2 * BB * HH) * sizeof(float);
    const size_t need_wht     = need_persist + (size_t)HH * HH * sizeof(float);

    if (ws_size >= need_persist) {
        unsigned int* flags = (unsigned int*)ws;
        float* hbuf = ws + 256;
        hipMemsetAsync(flags, 0, 1024, stream);

        const float* WhT = nullptr;
        if (ws_size >= need_wht) {
            float* whtp = ws + 256 + 2 * BB * HH;
            transpose_wh<<<dim3(32, 32), 256, 0, stream>>>(Wh, whtp);
            WhT = whtp;
        }

        void* kargs[] = {(void*)&Wh, (void*)&WhT, (void*)&h0, (void*)&out,
                         (void*)&flags, (void*)&hbuf};
        hipError_t rc = hipLaunchCooperativeKernel((const void*)rnn_persist,
                                                   dim3(WGN), dim3(256), kargs, 0,
                                                   stream);
        if (rc != hipSuccess) {
            rnn_persist<<<dim3(WGN), dim3(256), 0, stream>>>(Wh, WhT, h0, out,
                                                             flags, hbuf);
        }
    } else {
        // emergency fallback: multi-launch (correct, slow)
        float* cvec = ws;  // 1024 floats
        hipMemsetAsync(cvec, 0, HH * sizeof(float), stream);
        h0wh<<<64, 256, 0, stream>>>(Wh, h0, cvec);
        t0_kernel<<<BB * HH / 256, 256, 0, stream>>>(out, cvec);
        for (int t = 1; t < SS; ++t)
            rnn_step<<<dim3(64, 4), 256, 0, stream>>>(Wh, out, t);
    }
}

// Round 5
// 8664.459 us; speedup vs baseline: 5.2856x; 1.8085x over previous
//
#include <hip/hip_runtime.h>
#include <hip/hip_bf16.h>

// RNN: h_t = tanh(x_t @ Wx + h_{t-1} @ Wh + b), B=32, S=1024, D=H=1024, fp32.
// Phase 1: Xp = x@Wx + b in-place into d_out.
// Phase 2: ONE persistent kernel (Wh in LDS). Cross-WG h exchange via a
//   dedicated ping-pong buffer in d_ws touched ONLY by agent-scope atomics.
//   R5 change (single variable vs R4): flag store RELEASE -> RELAXED.
//   Rationale: all cross-WG data stores are sc1 atomics (L2-bypassing,
//   MALL-completing); __syncthreads()'s vmcnt(0) drain orders them before the
//   flag. RELEASE's buffer_wbl2 (full per-XCD L2 writeback walk, ~13us) is
//   redundant -> was ~90% of the measured 14.8us/step.

#define BB 32
#define SS 1024
#define DD 1024
#define HH 1024
#define NG 64   // n-groups of 16 cols
#define BG 4    // b-groups of 8 batches
#define WGN (NG * BG)

// ---------------- Phase 1: C = A @ W + bias ----------------
__global__ __launch_bounds__(256) void xw_gemm(const float* __restrict__ A,
                                               const float* __restrict__ W,
                                               const float* __restrict__ bias,
                                               float* __restrict__ C) {
    __shared__ float As[8][132];
    __shared__ float Bs[8][132];
    const int tid = threadIdx.x;
    const int n0 = blockIdx.x * 128;
    const int m0 = blockIdx.y * 128;
    const int tx = tid & 15;
    const int ty = tid >> 4;
    const int ar = tid >> 1;
    const int ak = (tid & 1) * 4;
    const int bk = tid >> 5;
    const int bn = (tid & 31) * 4;

    float acc[8][8];
#pragma unroll
    for (int i = 0; i < 8; ++i)
#pragma unroll
        for (int j = 0; j < 8; ++j) acc[i][j] = 0.f;

    for (int k0 = 0; k0 < DD; k0 += 8) {
        float4 av = *(const float4*)(A + (size_t)(m0 + ar) * DD + k0 + ak);
        float4 bv = *(const float4*)(W + (size_t)(k0 + bk) * HH + n0 + bn);
        __syncthreads();
        As[ak + 0][ar] = av.x;
        As[ak + 1][ar] = av.y;
        As[ak + 2][ar] = av.z;
        As[ak + 3][ar] = av.w;
        *(float4*)&Bs[bk][bn] = bv;
        __syncthreads();
#pragma unroll
        for (int k = 0; k < 8; ++k) {
            float4 a0 = *(const float4*)&As[k][ty * 4];
            float4 a1 = *(const float4*)&As[k][64 + ty * 4];
            float4 b0 = *(const float4*)&Bs[k][tx * 4];
            float4 b1 = *(const float4*)&Bs[k][64 + tx * 4];
            float ar_[8] = {a0.x, a0.y, a0.z, a0.w, a1.x, a1.y, a1.z, a1.w};
            float br_[8] = {b0.x, b0.y, b0.z, b0.w, b1.x, b1.y, b1.z, b1.w};
#pragma unroll
            for (int i = 0; i < 8; ++i)
#pragma unroll
                for (int j = 0; j < 8; ++j)
                    acc[i][j] = fmaf(ar_[i], br_[j], acc[i][j]);
        }
    }

    float4 bv0 = *(const float4*)(bias + n0 + tx * 4);
    float4 bv1 = *(const float4*)(bias + n0 + 64 + tx * 4);
#pragma unroll
    for (int i = 0; i < 8; ++i) {
        int m = m0 + ((i < 4) ? (ty * 4 + i) : (64 + ty * 4 + (i - 4)));
        float4 r0 = {acc[i][0] + bv0.x, acc[i][1] + bv0.y,
                     acc[i][2] + bv0.z, acc[i][3] + bv0.w};
        float4 r1 = {acc[i][4] + bv1.x, acc[i][5] + bv1.y,
                     acc[i][6] + bv1.z, acc[i][7] + bv1.w};
        *(float4*)(C + (size_t)m * HH + n0 + tx * 4) = r0;
        *(float4*)(C + (size_t)m * HH + n0 + 64 + tx * 4) = r1;
    }
}

// ---------------- WhT[n][k] = Wh[k][n] ----------------
__global__ __launch_bounds__(256) void transpose_wh(const float* __restrict__ in,
                                                    float* __restrict__ outT) {
    __shared__ float tile[32][33];
    const int tx = threadIdx.x & 31;
    const int ty = threadIdx.x >> 5;
    const int x0 = blockIdx.x * 32;
    const int y0 = blockIdx.y * 32;
    for (int r = ty; r < 32; r += 8)
        tile[r][tx] = in[(size_t)(y0 + r) * HH + x0 + tx];
    __syncthreads();
    for (int r = ty; r < 32; r += 8)
        outT[(size_t)(x0 + r) * HH + y0 + tx] = tile[tx][r];
}

// ---------------- Persistent RNN over all S steps ----------------
__global__ __launch_bounds__(256, 1) void rnn_persist(
    const float* __restrict__ Wh, const float* __restrict__ WhT,
    const float* __restrict__ h0, float* __restrict__ out,
    unsigned int* __restrict__ flags, float* __restrict__ hbuf) {
    __shared__ float WsT[16][1024];  // 64KB [col][k]
    __shared__ float hs[8][1024];    // 32KB [b][k]
    __shared__ float red[4][64];

    const int tid  = threadIdx.x;
    const int ng   = blockIdx.x & 63;
    const int bg   = blockIdx.x >> 6;
    const int n0   = ng * 16;
    const int b0   = bg * 8;
    const int lane = tid & 63;
    const int wv   = tid >> 6;
    const int ns   = tid >> 7;
    const int kq   = tid & 127;
    unsigned int* myflags = flags + bg * 64;

    // --- one-time: Wh column-slice (transposed) into LDS ---
    {
        const int c   = tid >> 4;
        const int t16 = tid & 15;
        if (WhT) {
            const float* src = WhT + (size_t)(n0 + c) * HH;
#pragma unroll
            for (int j = 0; j < 16; ++j) {
                int k4 = (j * 16 + t16) * 4;
                *(float4*)&WsT[c][k4] = *(const float4*)(src + k4);
            }
        } else {
            for (int j = 0; j < 64; ++j) {
                int k = j * 16 + t16;
                WsT[c][k] = Wh[(size_t)k * HH + n0 + c];
            }
        }
    }

    // epilogue mapping: thread (tid<128) owns output (eb, ec)
    size_t xp_base = 0;
    int hb_off = 0;
    if (tid < 128) {
        int l   = tid & 63;
        int idx = (int)(__brev((unsigned)l) >> 26);
        int eb  = idx >> 3;
        int ec  = (tid >> 6) * 8 + (idx & 7);
        xp_base = ((size_t)(b0 + eb) * SS) * HH + (n0 + ec);
        hb_off  = (b0 + eb) * HH + (n0 + ec);
    }
    __syncthreads();

    for (int t = 0; t < SS; ++t) {
        // ---- prefetch own Xp (plain load, independent of sync) ----
        float xp = 0.f;
        if (tid < 128) xp = out[xp_base + (size_t)t * HH];

        // ---- wait for h_{t-1} then stage it into LDS ----
        if (t == 0) {
#pragma unroll
            for (int j = 0; j < 8; ++j) {
                int f4 = tid + 256 * j;
                int r = f4 >> 8, c4 = (f4 & 255) * 4;
                *(float4*)&hs[r][c4] = *(const float4*)(h0 + c4);
            }
        } else {
            if (wv == 0) {
                const unsigned target = (unsigned)t;
                for (;;) {
                    unsigned v = __hip_atomic_load(&myflags[lane], __ATOMIC_RELAXED,
                                                   __HIP_MEMORY_SCOPE_AGENT);
                    if (__all((int)(v >= target))) break;
                    __builtin_amdgcn_s_sleep(1);
                }
            }
            __syncthreads();
            asm volatile("" ::: "memory");
            // hbuf[(t-1)&1] is touched ONLY via agent-scope atomics (8B each)
            const unsigned long long* hsrc =
                (const unsigned long long*)(hbuf + (size_t)((t - 1) & 1) * BB * HH);
#pragma unroll
            for (int j = 0; j < 16; ++j) {
                int idx = tid + 256 * j;       // 0..4095 over 8 rows x 512 ulls
                int r   = idx >> 9;
                int c2  = idx & 511;
                unsigned long long u = __hip_atomic_load(
                    hsrc + (size_t)(b0 + r) * (HH / 2) + c2,
                    __ATOMIC_RELAXED, __HIP_MEMORY_SCOPE_AGENT);
                *(unsigned long long*)&hs[r][c2 * 2] = u;
            }
        }
        __syncthreads();

        // ---- 512 FMA per thread ----
        float a[64];
#pragma unroll
        for (int i = 0; i < 64; ++i) a[i] = 0.f;
#pragma unroll
        for (int half = 0; half < 2; ++half) {
            const int kb = half * 512 + kq * 4;
            float4 w[8], h[8];
#pragma unroll
            for (int c = 0; c < 8; ++c) w[c] = *(const float4*)&WsT[ns * 8 + c][kb];
#pragma unroll
            for (int b = 0; b < 8; ++b) h[b] = *(const float4*)&hs[b][kb];
#pragma unroll
            for (int b = 0; b < 8; ++b)
#pragma unroll
                for (int c = 0; c < 8; ++c)
                    a[b * 8 + c] += h[b].x * w[c].x + h[b].y * w[c].y +
                                    h[b].z * w[c].z + h[b].w * w[c].w;
        }

        // ---- folding in-wave reduce over kq ----
        int s = 64;
#pragma unroll
        for (int m = 1; m <= 32; m <<= 1) {
            const int hs_ = s >> 1;
            const bool hi = (lane & m) != 0;
#pragma unroll
            for (int i = 0; i < hs_; ++i) {
                float lo = a[i], hg = a[i + hs_];
                a[i]       = hi ? hg : lo;
                a[i + hs_] = hi ? lo : hg;
            }
#pragma unroll
            for (int i = 0; i < hs_; ++i) a[i] += __shfl_xor(a[i + hs_], m, 64);
            s = hs_;
        }

        red[wv][lane] = a[0];
        __syncthreads();

        if (tid < 128) {
            const int l = tid & 63;
            const int nss = tid >> 6;
            float v = red[nss * 2][l] + red[nss * 2 + 1][l];
            float hv = tanhf(v + xp);
            out[xp_base + (size_t)t * HH] = hv;          // plain (write-only in-kernel)
            __hip_atomic_store(hbuf + (size_t)(t & 1) * BB * HH + hb_off, hv,
                               __ATOMIC_RELAXED, __HIP_MEMORY_SCOPE_AGENT);
        }

        // ---- release: __syncthreads drains vmcnt(0) (sc1 stores at MALL),
        //      then RELAXED per-WG flag store (no buffer_wbl2 L2 walk) ----
        __syncthreads();
        if (tid == 0)
            __hip_atomic_store(&myflags[ng], (unsigned)(t + 1), __ATOMIC_RELAXED,
                               __HIP_MEMORY_SCOPE_AGENT);
    }
}

// ---------------- fallback path (tiny ws): multi-launch steps ----------------
__global__ __launch_bounds__(256) void h0wh(const float* __restrict__ Wh,
                                            const float* __restrict__ h0,
                                            float* __restrict__ c) {
    const int g = blockIdx.x;
    const int n = threadIdx.x * 4;
    float4 a = {0.f, 0.f, 0.f, 0.f};
    for (int kk = 0; kk < 16; ++kk) {
        int k = g * 16 + kk;
        float hv = h0[k];
        float4 w = *(const float4*)(Wh + (size_t)k * HH + n);
        a.x += hv * w.x; a.y += hv * w.y; a.z += hv * w.z; a.w += hv * w.w;
    }
    atomicAdd(&c[n + 0], a.x);
    atomicAdd(&c[n + 1], a.y);
    atomicAdd(&c[n + 2], a.z);
    atomicAdd(&c[n + 3], a.w);
}

__global__ __launch_bounds__(256) void t0_kernel(float* __restrict__ out,
                                                 const float* __restrict__ c) {
    const int idx = blockIdx.x * 256 + threadIdx.x;
    const int b = idx >> 10;
    const int n = idx & 1023;
    const size_t p = (size_t)b * SS * HH + n;
    out[p] = tanhf(out[p] + c[n]);
}

__global__ __launch_bounds__(256) void rnn_step(const float* __restrict__ Wh,
                                                float* __restrict__ out, int t) {
    __shared__ float hsl[8][1028];
    __shared__ float ps[256];
    const int tid = threadIdx.x;
    const int n0 = blockIdx.x * 16;
    const int b0 = blockIdx.y * 8;
    for (int i = tid; i < 8 * 256; i += 256) {
        int r = i >> 8;
        int c = (i & 255) << 2;
        *(float4*)&hsl[r][c] =
            *(const float4*)(out + ((size_t)(b0 + r) * SS + (t - 1)) * HH + c);
    }
    __syncthreads();
    const int nl = tid & 15;
    const int bl = (tid >> 4) & 7;
    const int half = tid >> 7;
    const int n = n0 + nl;
    float acc = 0.f;
    const float* hrow = &hsl[bl][half * 512];
    const float* wcol = Wh + (size_t)(half * 512) * HH + n;
#pragma unroll 4
    for (int k = 0; k < 512; k += 4) {
        float4 h4 = *(const float4*)(hrow + k);
        acc += h4.x * wcol[(size_t)(k + 0) * HH];
        acc += h4.y * wcol[(size_t)(k + 1) * HH];
        acc += h4.z * wcol[(size_t)(k + 2) * HH];
        acc += h4.w * wcol[(size_t)(k + 3) * HH];
    }
    ps[tid] = acc;
    __syncthreads();
    if (tid < 128) {
        const size_t obase = ((size_t)(b0 + bl) * SS + t) * HH + n;
        out[obase] = tanhf(out[obase] + ps[tid] + ps[tid + 128]);
    }
}

extern "C" void kernel_launch(void* const* d_in, const int* in_sizes, int n_in,
                              void* d_out, int out_size, void* d_ws, size_t ws_size,
                              hipStream_t stream) {
    const float* x    = (const float*)d_in[0];
    const float* Wx   = (const float*)d_in[1];
    const float* Wh   = (const float*)d_in[2];
    const float* bias = (const float*)d_in[3];
    const float* h0   = (const float*)d_in[4];
    float* out = (float*)d_out;
    float* ws  = (float*)d_ws;

    // Phase 1: Xp = x@Wx + b -> d_out
    xw_gemm<<<dim3(8, 256), 256, 0, stream>>>(x, Wx, bias, out);

    // ws layout: [0..255] flags (uint) | [256..] hbuf 2*32*1024 f | WhT 1024*1024 f
    const size_t need_persist = (size_t)(256 + 2 * BB * HH) * sizeof(float);
    const size_t need_wht     = need_persist + (size_t)HH * HH * sizeof(float);

    if (ws_size >= need_persist) {
        unsigned int* flags = (unsigned int*)ws;
        float* hbuf = ws + 256;
        hipMemsetAsync(flags, 0, 1024, stream);

        const float* WhT = nullptr;
        if (ws_size >= need_wht) {
            float* whtp = ws + 256 + 2 * BB * HH;
            transpose_wh<<<dim3(32, 32), 256, 0, stream>>>(Wh, whtp);
            WhT = whtp;
        }

        void* kargs[] = {(void*)&Wh, (void*)&WhT, (void*)&h0, (void*)&out,
                         (void*)&flags, (void*)&hbuf};
        hipError_t rc = hipLaunchCooperativeKernel((const void*)rnn_persist,
                                                   dim3(WGN), dim3(256), kargs, 0,
                                                   stream);
        if (rc != hipSuccess) {
            rnn_persist<<<dim3(WGN), dim3(256), 0, stream>>>(Wh, WhT, h0, out,
                                                             flags, hbuf);
        }
    } else {
        // emergency fallback: multi-launch (correct, slow)
        float* cvec = ws;  // 1024 floats
        hipMemsetAsync(cvec, 0, HH * sizeof(float), stream);
        h0wh<<<64, 256, 0, stream>>>(Wh, h0, cvec);
        t0_kernel<<<BB * HH / 256, 256, 0, stream>>>(out, cvec);
        for (int t = 1; t < SS; ++t)
            rnn_step<<<dim3(64, 4), 256, 0, stream>>>(Wh, out, t);
    }
}

// Round 7
// 5259.903 us; speedup vs baseline: 8.7067x; 1.6473x over previous
//
#include <hip/hip_runtime.h>
#include <hip/hip_bf16.h>

// RNN: h_t = tanh(x_t @ Wx + h_{t-1} @ Wh + b), B=32, S=1024, D=H=1024, fp32.
// Phase 1: Xp = x@Wx + b in-place into d_out.
// Phase 2: ONE persistent kernel (Wh in LDS), 4 independent batch-chains of
//   64 WGs. R7 = R6 + restored COMPILER FENCES at sync boundaries.
//   R6's failure diagnosis: __syncthreads is a workgroup-scope fence; LLVM may
//   hoist AGENT-scope relaxed atomic loads above it (waves 1-3's staging loads
//   have no pre-barrier dependency) -> stale h. R5 was protected by an
//   asm volatile memory clobber I dropped in R6. Restored + symmetric fence
//   around the publish->increment boundary (sink hazard).

#define BB 32
#define SS 1024
#define DD 1024
#define HH 1024
#define NG 64   // n-groups of 16 cols
#define BG 4    // b-groups of 8 batches
#define WGN (NG * BG)

#define CFENCE() asm volatile("" ::: "memory")

typedef unsigned long long ull;

// ---------------- Phase 1: C = A @ W + bias ----------------
__global__ __launch_bounds__(256) void xw_gemm(const float* __restrict__ A,
                                               const float* __restrict__ W,
                                               const float* __restrict__ bias,
                                               float* __restrict__ C) {
    __shared__ float As[8][132];
    __shared__ float Bs[8][132];
    const int tid = threadIdx.x;
    const int n0 = blockIdx.x * 128;
    const int m0 = blockIdx.y * 128;
    const int tx = tid & 15;
    const int ty = tid >> 4;
    const int ar = tid >> 1;
    const int ak = (tid & 1) * 4;
    const int bk = tid >> 5;
    const int bn = (tid & 31) * 4;

    float acc[8][8];
#pragma unroll
    for (int i = 0; i < 8; ++i)
#pragma unroll
        for (int j = 0; j < 8; ++j) acc[i][j] = 0.f;

    for (int k0 = 0; k0 < DD; k0 += 8) {
        float4 av = *(const float4*)(A + (size_t)(m0 + ar) * DD + k0 + ak);
        float4 bv = *(const float4*)(W + (size_t)(k0 + bk) * HH + n0 + bn);
        __syncthreads();
        As[ak + 0][ar] = av.x;
        As[ak + 1][ar] = av.y;
        As[ak + 2][ar] = av.z;
        As[ak + 3][ar] = av.w;
        *(float4*)&Bs[bk][bn] = bv;
        __syncthreads();
#pragma unroll
        for (int k = 0; k < 8; ++k) {
            float4 a0 = *(const float4*)&As[k][ty * 4];
            float4 a1 = *(const float4*)&As[k][64 + ty * 4];
            float4 b0 = *(const float4*)&Bs[k][tx * 4];
            float4 b1 = *(const float4*)&Bs[k][64 + tx * 4];
            float ar_[8] = {a0.x, a0.y, a0.z, a0.w, a1.x, a1.y, a1.z, a1.w};
            float br_[8] = {b0.x, b0.y, b0.z, b0.w, b1.x, b1.y, b1.z, b1.w};
#pragma unroll
            for (int i = 0; i < 8; ++i)
#pragma unroll
                for (int j = 0; j < 8; ++j)
                    acc[i][j] = fmaf(ar_[i], br_[j], acc[i][j]);
        }
    }

    float4 bv0 = *(const float4*)(bias + n0 + tx * 4);
    float4 bv1 = *(const float4*)(bias + n0 + 64 + tx * 4);
#pragma unroll
    for (int i = 0; i < 8; ++i) {
        int m = m0 + ((i < 4) ? (ty * 4 + i) : (64 + ty * 4 + (i - 4)));
        float4 r0 = {acc[i][0] + bv0.x, acc[i][1] + bv0.y,
                     acc[i][2] + bv0.z, acc[i][3] + bv0.w};
        float4 r1 = {acc[i][4] + bv1.x, acc[i][5] + bv1.y,
                     acc[i][6] + bv1.z, acc[i][7] + bv1.w};
        *(float4*)(C + (size_t)m * HH + n0 + tx * 4) = r0;
        *(float4*)(C + (size_t)m * HH + n0 + 64 + tx * 4) = r1;
    }
}

// ---------------- WhT[n][k] = Wh[k][n] ----------------
__global__ __launch_bounds__(256) void transpose_wh(const float* __restrict__ in,
                                                    float* __restrict__ outT) {
    __shared__ float tile[32][33];
    const int tx = threadIdx.x & 31;
    const int ty = threadIdx.x >> 5;
    const int x0 = blockIdx.x * 32;
    const int y0 = blockIdx.y * 32;
    for (int r = ty; r < 32; r += 8)
        tile[r][tx] = in[(size_t)(y0 + r) * HH + x0 + tx];
    __syncthreads();
    for (int r = ty; r < 32; r += 8)
        outT[(size_t)(x0 + r) * HH + y0 + tx] = tile[tx][r];
}

// ---------------- Persistent RNN over all S steps ----------------
#define FMA_HALF(HALF)                                                         \
    {                                                                          \
        const int kb = (HALF) * 512 + kq * 4;                                  \
        float4 w[8], h[8];                                                     \
        _Pragma("unroll") for (int c = 0; c < 8; ++c)                          \
            w[c] = *(const float4*)&WsT[ns * 8 + c][kb];                       \
        _Pragma("unroll") for (int b = 0; b < 8; ++b)                          \
            h[b] = *(const float4*)&hs[b][kb];                                 \
        _Pragma("unroll") for (int b = 0; b < 8; ++b)                          \
            _Pragma("unroll") for (int c = 0; c < 8; ++c)                      \
                a[b * 8 + c] += h[b].x * w[c].x + h[b].y * w[c].y +            \
                                h[b].z * w[c].z + h[b].w * w[c].w;             \
    }

__global__ __launch_bounds__(256, 1) void rnn_persist(
    const float* __restrict__ Wh, const float* __restrict__ WhT,
    const float* __restrict__ h0, float* __restrict__ out,
    unsigned int* __restrict__ flags, float* __restrict__ hbuf) {
    __shared__ float WsT[16][1024];  // 64KB [col][k]
    __shared__ float hs[8][1024];    // 32KB [b][k]
    __shared__ float red[4][64];
    __shared__ float hout[8][16];    // linearized h tile for coalesced publish

    const int tid  = threadIdx.x;
    const int ng   = blockIdx.x & 63;
    const int bg   = blockIdx.x >> 6;
    const int n0   = ng * 16;
    const int b0   = bg * 8;
    const int lane = tid & 63;
    const int wv   = tid >> 6;
    const int ns   = tid >> 7;
    const int kq   = tid & 127;
    unsigned int* cnt = flags + bg * 64;  // one counter per bgroup, 256B apart

    // --- one-time: Wh column-slice (transposed) into LDS ---
    {
        const int c   = tid >> 4;
        const int t16 = tid & 15;
        if (WhT) {
            const float* src = WhT + (size_t)(n0 + c) * HH;
#pragma unroll
            for (int j = 0; j < 16; ++j) {
                int k4 = (j * 16 + t16) * 4;
                *(float4*)&WsT[c][k4] = *(const float4*)(src + k4);
            }
        } else {
            for (int j = 0; j < 64; ++j) {
                int k = j * 16 + t16;
                WsT[c][k] = Wh[(size_t)k * HH + n0 + c];
            }
        }
    }

    // epilogue mapping: thread (tid<128) owns output (eb, ec)
    size_t xp_base = 0;
    int eb = 0, ec = 0;
    if (tid < 128) {
        int l   = tid & 63;
        int idx = (int)(__brev((unsigned)l) >> 26);
        eb = idx >> 3;
        ec = (tid >> 6) * 8 + (idx & 7);
        xp_base = ((size_t)(b0 + eb) * SS) * HH + (n0 + ec);
    }
    __syncthreads();

    for (int t = 0; t < SS; ++t) {
        // ---- prefetch own Xp (plain load, independent of sync) ----
        float xp = 0.f;
        if (tid < 128) xp = out[xp_base + (size_t)t * HH];

        float a[64];
#pragma unroll
        for (int i = 0; i < 64; ++i) a[i] = 0.f;

        if (t == 0) {
#pragma unroll
            for (int j = 0; j < 8; ++j) {
                int f4 = tid + 256 * j;
                int r = f4 >> 8, c4 = (f4 & 255) * 4;
                *(float4*)&hs[r][c4] = *(const float4*)(h0 + c4);
            }
            __syncthreads();
            FMA_HALF(0)
            FMA_HALF(1)
        } else {
            // ---- gate: single-word scalar spin (cnt == 64*t when all
            //      producers finished step t-1) ----
            if (tid == 0) {
                const unsigned target = (unsigned)t * 64u;
                while (__hip_atomic_load(cnt, __ATOMIC_RELAXED,
                                         __HIP_MEMORY_SCOPE_AGENT) < target) {
                }
            }
            CFENCE();
            __syncthreads();
            CFENCE();   // block hoisting agent-scope loads above the gate

            // ---- async-stage split: issue ALL 16 sc1 loads, then
            //      write/compute half0 while half1 is still in flight ----
            const ull* hsrc = (const ull*)(hbuf + (size_t)((t - 1) & 1) * BB * HH);
            ull hr[16];
#pragma unroll
            for (int j = 0; j < 8; ++j)
                hr[j] = __hip_atomic_load(hsrc + (size_t)(b0 + j) * 512 + tid,
                                          __ATOMIC_RELAXED, __HIP_MEMORY_SCOPE_AGENT);
#pragma unroll
            for (int j = 0; j < 8; ++j)
                hr[8 + j] = __hip_atomic_load(hsrc + (size_t)(b0 + j) * 512 + 256 + tid,
                                              __ATOMIC_RELAXED, __HIP_MEMORY_SCOPE_AGENT);
#pragma unroll
            for (int j = 0; j < 8; ++j)
                *(ull*)&hs[j][tid * 2] = hr[j];
            __syncthreads();
            FMA_HALF(0)
#pragma unroll
            for (int j = 0; j < 8; ++j)
                *(ull*)&hs[j][512 + tid * 2] = hr[8 + j];
            __syncthreads();
            FMA_HALF(1)
        }

        // ---- folding in-wave reduce over kq ----
        int s = 64;
#pragma unroll
        for (int m = 1; m <= 32; m <<= 1) {
            const int hs_ = s >> 1;
            const bool hi = (lane & m) != 0;
#pragma unroll
            for (int i = 0; i < hs_; ++i) {
                float lo = a[i], hg = a[i + hs_];
                a[i]       = hi ? hg : lo;
                a[i + hs_] = hi ? lo : hg;
            }
#pragma unroll
            for (int i = 0; i < hs_; ++i) a[i] += __shfl_xor(a[i + hs_], m, 64);
            s = hs_;
        }

        red[wv][lane] = a[0];
        __syncthreads();

        // ---- epilogue: finalize, write out (plain), linearize into hout ----
        if (tid < 128) {
            const int l = tid & 63;
            const int nss = tid >> 6;
            float v = red[nss * 2][l] + red[nss * 2 + 1][l];
            float hv = tanhf(v + xp);
            out[xp_base + (size_t)t * HH] = hv;  // plain (write-only in-kernel)
            hout[eb][ec] = hv;
        }
        __syncthreads();

        // ---- coalesced h publish: 64 contiguous 8B sc1 stores ----
        if (tid < 64) {
            const int r  = tid >> 3;
            const int c2 = tid & 7;
            ull u = *(const ull*)&hout[r][c2 * 2];
            __hip_atomic_store(
                (ull*)(hbuf + (size_t)(t & 1) * BB * HH) +
                    (size_t)(b0 + r) * 512 + (n0 >> 1) + c2,
                u, __ATOMIC_RELAXED, __HIP_MEMORY_SCOPE_AGENT);
        }

        // ---- barrier drains vmcnt(0) (sc1 stores ACKed at MALL), then
        //      RELAXED aggregated counter add; fences pin store/add order ----
        CFENCE();
        __syncthreads();
        CFENCE();   // block sinking publish stores below / hoisting add above
        if (tid == 0)
            __hip_atomic_fetch_add(cnt, 1u, __ATOMIC_RELAXED,
                                   __HIP_MEMORY_SCOPE_AGENT);
    }
}

// ---------------- fallback path (tiny ws): multi-launch steps ----------------
__global__ __launch_bounds__(256) void h0wh(const float* __restrict__ Wh,
                                            const float* __restrict__ h0,
                                            float* __restrict__ c) {
    const int g = blockIdx.x;
    const int n = threadIdx.x * 4;
    float4 a = {0.f, 0.f, 0.f, 0.f};
    for (int kk = 0; kk < 16; ++kk) {
        int k = g * 16 + kk;
        float hv = h0[k];
        float4 w = *(const float4*)(Wh + (size_t)k * HH + n);
        a.x += hv * w.x; a.y += hv * w.y; a.z += hv * w.z; a.w += hv * w.w;
    }
    atomicAdd(&c[n + 0], a.x);
    atomicAdd(&c[n + 1], a.y);
    atomicAdd(&c[n + 2], a.z);
    atomicAdd(&c[n + 3], a.w);
}

__global__ __launch_bounds__(256) void t0_kernel(float* __restrict__ out,
                                                 const float* __restrict__ c) {
    const int idx = blockIdx.x * 256 + threadIdx.x;
    const int b = idx >> 10;
    const int n = idx & 1023;
    const size_t p = (size_t)b * SS * HH + n;
    out[p] = tanhf(out[p] + c[n]);
}

__global__ __launch_bounds__(256) void rnn_step(const float* __restrict__ Wh,
                                                float* __restrict__ out, int t) {
    __shared__ float hsl[8][1028];
    __shared__ float ps[256];
    const int tid = threadIdx.x;
    const int n0 = blockIdx.x * 16;
    const int b0 = blockIdx.y * 8;
    for (int i = tid; i < 8 * 256; i += 256) {
        int r = i >> 8;
        int c = (i & 255) << 2;
        *(float4*)&hsl[r][c] =
            *(const float4*)(out + ((size_t)(b0 + r) * SS + (t - 1)) * HH + c);
    }
    __syncthreads();
    const int nl = tid & 15;
    const int bl = (tid >> 4) & 7;
    const int half_ = tid >> 7;
    const int n = n0 + nl;
    float acc = 0.f;
    const float* hrow = &hsl[bl][half_ * 512];
    const float* wcol = Wh + (size_t)(half_ * 512) * HH + n;
#pragma unroll 4
    for (int k = 0; k < 512; k += 4) {
        float4 h4 = *(const float4*)(hrow + k);
        acc += h4.x * wcol[(size_t)(k + 0) * HH];
        acc += h4.y * wcol[(size_t)(k + 1) * HH];
        acc += h4.z * wcol[(size_t)(k + 2) * HH];
        acc += h4.w * wcol[(size_t)(k + 3) * HH];
    }
    ps[tid] = acc;
    __syncthreads();
    if (tid < 128) {
        const size_t obase = ((size_t)(b0 + bl) * SS + t) * HH + n;
        out[obase] = tanhf(out[obase] + ps[tid] + ps[tid + 128]);
    }
}

extern "C" void kernel_launch(void* const* d_in, const int* in_sizes, int n_in,
                              void* d_out, int out_size, void* d_ws, size_t ws_size,
                              hipStream_t stream) {
    const float* x    = (const float*)d_in[0];
    const float* Wx   = (const float*)d_in[1];
    const float* Wh   = (const float*)d_in[2];
    const float* bias = (const float*)d_in[3];
    const float* h0   = (const float*)d_in[4];
    float* out = (float*)d_out;
    float* ws  = (float*)d_ws;

    // Phase 1: Xp = x@Wx + b -> d_out
    xw_gemm<<<dim3(8, 256), 256, 0, stream>>>(x, Wx, bias, out);

    // ws layout: [0..255] counters (uint) | [256..] hbuf 2*32*1024 f | WhT 1024^2 f
    const size_t need_persist = (size_t)(256 + 2 * BB * HH) * sizeof(float);
    const size_t need_wht     = need_persist + (size_t)HH * HH * sizeof(float);

    if (ws_size >= need_persist) {
        unsigned int* flags = (unsigned int*)ws;
        float* hbuf = ws + 256;
        hipMemsetAsync(flags, 0, 1024, stream);

        const float* WhT = nullptr;
        if (ws_size >= need_wht) {
            float* whtp = ws + 256 + 2 * BB * HH;
            transpose_wh<<<dim3(32, 32), 256, 0, stream>>>(Wh, whtp);
            WhT = whtp;
        }

        void* kargs[] = {(void*)&Wh, (void*)&WhT, (void*)&h0, (void*)&out,
                         (void*)&flags, (void*)&hbuf};
        hipError_t rc = hipLaunchCooperativeKernel((const void*)rnn_persist,
                                                   dim3(WGN), dim3(256), kargs, 0,
                                                   stream);
        if (rc != hipSuccess) {
            rnn_persist<<<dim3(WGN), dim3(256), 0, stream>>>(Wh, WhT, h0, out,
                                                             flags, hbuf);
        }
    } else {
        // emergency fallback: multi-launch (correct, slow)
        float* cvec = ws;  // 1024 floats
        hipMemsetAsync(cvec, 0, HH * sizeof(float), stream);
        h0wh<<<64, 256, 0, stream>>>(Wh, h0, cvec);
        t0_kernel<<<BB * HH / 256, 256, 0, stream>>>(out, cvec);
        for (int t = 1; t < SS; ++t)
            rnn_step<<<dim3(64, 4), 256, 0, stream>>>(Wh, out, t);
    }
}

// Round 9
// 5093.040 us; speedup vs baseline: 8.9920x; 1.0328x over previous
//
#include <hip/hip_runtime.h>
#include <hip/hip_bf16.h>

// RNN: h_t = tanh(x_t @ Wx + h_{t-1} @ Wh + b), B=32, S=1024, D=H=1024, fp32.
// Phase 1: Xp = x@Wx + b in-place into d_out.
// Phase 2: ONE persistent kernel, 4 independent batch-chains of 64 WGs.
// R9 = R7's EXACT sync protocol (fetch_add counter gate + CFENCEs — proven
//   over full replay sets) + Wh-in-registers (the one R8 change that is
//   deterministic). R8's per-WG-flag gate failed post-timing re-validation
//   (first launch correct, a replay corrupted) -> reverted. Single variable
//   vs R7: Wh regs instead of WsT LDS (16 fewer ds_read_b128/thread/step).

#define BB 32
#define SS 1024
#define DD 1024
#define HH 1024
#define NG 64   // n-groups of 16 cols
#define BG 4    // b-groups of 8 batches
#define WGN (NG * BG)

#define CFENCE() asm volatile("" ::: "memory")

typedef unsigned long long ull;

// ---------------- Phase 1: C = A @ W + bias ----------------
__global__ __launch_bounds__(256) void xw_gemm(const float* __restrict__ A,
                                               const float* __restrict__ W,
                                               const float* __restrict__ bias,
                                               float* __restrict__ C) {
    __shared__ float As[8][132];
    __shared__ float Bs[8][132];
    const int tid = threadIdx.x;
    const int n0 = blockIdx.x * 128;
    const int m0 = blockIdx.y * 128;
    const int tx = tid & 15;
    const int ty = tid >> 4;
    const int ar = tid >> 1;
    const int ak = (tid & 1) * 4;
    const int bk = tid >> 5;
    const int bn = (tid & 31) * 4;

    float acc[8][8];
#pragma unroll
    for (int i = 0; i < 8; ++i)
#pragma unroll
        for (int j = 0; j < 8; ++j) acc[i][j] = 0.f;

    for (int k0 = 0; k0 < DD; k0 += 8) {
        float4 av = *(const float4*)(A + (size_t)(m0 + ar) * DD + k0 + ak);
        float4 bv = *(const float4*)(W + (size_t)(k0 + bk) * HH + n0 + bn);
        __syncthreads();
        As[ak + 0][ar] = av.x;
        As[ak + 1][ar] = av.y;
        As[ak + 2][ar] = av.z;
        As[ak + 3][ar] = av.w;
        *(float4*)&Bs[bk][bn] = bv;
        __syncthreads();
#pragma unroll
        for (int k = 0; k < 8; ++k) {
            float4 a0 = *(const float4*)&As[k][ty * 4];
            float4 a1 = *(const float4*)&As[k][64 + ty * 4];
            float4 b0 = *(const float4*)&Bs[k][tx * 4];
            float4 b1 = *(const float4*)&Bs[k][64 + tx * 4];
            float ar_[8] = {a0.x, a0.y, a0.z, a0.w, a1.x, a1.y, a1.z, a1.w};
            float br_[8] = {b0.x, b0.y, b0.z, b0.w, b1.x, b1.y, b1.z, b1.w};
#pragma unroll
            for (int i = 0; i < 8; ++i)
#pragma unroll
                for (int j = 0; j < 8; ++j)
                    acc[i][j] = fmaf(ar_[i], br_[j], acc[i][j]);
        }
    }

    float4 bv0 = *(const float4*)(bias + n0 + tx * 4);
    float4 bv1 = *(const float4*)(bias + n0 + 64 + tx * 4);
#pragma unroll
    for (int i = 0; i < 8; ++i) {
        int m = m0 + ((i < 4) ? (ty * 4 + i) : (64 + ty * 4 + (i - 4)));
        float4 r0 = {acc[i][0] + bv0.x, acc[i][1] + bv0.y,
                     acc[i][2] + bv0.z, acc[i][3] + bv0.w};
        float4 r1 = {acc[i][4] + bv1.x, acc[i][5] + bv1.y,
                     acc[i][6] + bv1.z, acc[i][7] + bv1.w};
        *(float4*)(C + (size_t)m * HH + n0 + tx * 4) = r0;
        *(float4*)(C + (size_t)m * HH + n0 + 64 + tx * 4) = r1;
    }
}

// ---------------- WhT[n][k] = Wh[k][n] ----------------
__global__ __launch_bounds__(256) void transpose_wh(const float* __restrict__ in,
                                                    float* __restrict__ outT) {
    __shared__ float tile[32][33];
    const int tx = threadIdx.x & 31;
    const int ty = threadIdx.x >> 5;
    const int x0 = blockIdx.x * 32;
    const int y0 = blockIdx.y * 32;
    for (int r = ty; r < 32; r += 8)
        tile[r][tx] = in[(size_t)(y0 + r) * HH + x0 + tx];
    __syncthreads();
    for (int r = ty; r < 32; r += 8)
        outT[(size_t)(x0 + r) * HH + y0 + tx] = tile[tx][r];
}

// ---------------- Persistent RNN over all S steps ----------------
// Thread tile 8b x 8n x 8k; Wh fragment (8 cols x 8 k-slots = 64 floats) is
// loop-invariant and lives in wreg[2][8] (float4) for the whole kernel.
#define FMA_HALF(HALF)                                                         \
    {                                                                          \
        const int kb = (HALF) * 512 + kq * 4;                                  \
        float4 h[8];                                                           \
        _Pragma("unroll") for (int b = 0; b < 8; ++b)                          \
            h[b] = *(const float4*)&hs[b][kb];                                 \
        _Pragma("unroll") for (int b = 0; b < 8; ++b)                          \
            _Pragma("unroll") for (int c = 0; c < 8; ++c)                      \
                a[b * 8 + c] += h[b].x * wreg[HALF][c].x +                     \
                                h[b].y * wreg[HALF][c].y +                     \
                                h[b].z * wreg[HALF][c].z +                     \
                                h[b].w * wreg[HALF][c].w;                      \
    }

__global__ __launch_bounds__(256, 1) void rnn_persist(
    const float* __restrict__ Wh, const float* __restrict__ WhT,
    const float* __restrict__ h0, float* __restrict__ out,
    unsigned int* __restrict__ flags, float* __restrict__ hbuf) {
    __shared__ float hs[8][1024];    // 32KB [b][k]
    __shared__ float red[4][64];
    __shared__ float hout[8][16];    // linearized h tile for coalesced publish

    const int tid  = threadIdx.x;
    const int ng   = blockIdx.x & 63;
    const int bg   = blockIdx.x >> 6;
    const int n0   = ng * 16;
    const int b0   = bg * 8;
    const int lane = tid & 63;
    const int wv   = tid >> 6;
    const int ns   = tid >> 7;
    const int kq   = tid & 127;
    unsigned int* cnt = flags + bg * 64;  // one counter per bgroup, 256B apart

    // --- one-time: this thread's Wh fragment into registers ---
    // needs cols n0+ns*8 .. +7 at k in {4kq..4kq+3} u {512+4kq..+3}
    float4 wreg[2][8];
    if (WhT) {
        const float* base = WhT + (size_t)(n0 + ns * 8) * HH + kq * 4;
#pragma unroll
        for (int c = 0; c < 8; ++c) {
            wreg[0][c] = *(const float4*)(base + (size_t)c * HH);
            wreg[1][c] = *(const float4*)(base + (size_t)c * HH + 512);
        }
    } else {
#pragma unroll
        for (int c = 0; c < 8; ++c) {
            float v[8];
            for (int j = 0; j < 4; ++j)
                v[j] = Wh[(size_t)(kq * 4 + j) * HH + n0 + ns * 8 + c];
            for (int j = 0; j < 4; ++j)
                v[4 + j] = Wh[(size_t)(512 + kq * 4 + j) * HH + n0 + ns * 8 + c];
            wreg[0][c] = {v[0], v[1], v[2], v[3]};
            wreg[1][c] = {v[4], v[5], v[6], v[7]};
        }
    }

    // epilogue mapping: thread (tid<128) owns output (eb, ec)
    size_t xp_base = 0;
    int eb = 0, ec = 0;
    if (tid < 128) {
        int l   = tid & 63;
        int idx = (int)(__brev((unsigned)l) >> 26);
        eb = idx >> 3;
        ec = (tid >> 6) * 8 + (idx & 7);
        xp_base = ((size_t)(b0 + eb) * SS) * HH + (n0 + ec);
    }

    for (int t = 0; t < SS; ++t) {
        // ---- prefetch own Xp (plain load, independent of sync) ----
        float xp = 0.f;
        if (tid < 128) xp = out[xp_base + (size_t)t * HH];

        float a[64];
#pragma unroll
        for (int i = 0; i < 64; ++i) a[i] = 0.f;

        if (t == 0) {
#pragma unroll
            for (int j = 0; j < 8; ++j) {
                int f4 = tid + 256 * j;
                int r = f4 >> 8, c4 = (f4 & 255) * 4;
                *(float4*)&hs[r][c4] = *(const float4*)(h0 + c4);
            }
            __syncthreads();
            FMA_HALF(0)
            FMA_HALF(1)
        } else {
            // ---- gate: single-word scalar spin (cnt == 64*t when all
            //      producers finished step t-1) — R7's proven protocol ----
            if (tid == 0) {
                const unsigned target = (unsigned)t * 64u;
                while (__hip_atomic_load(cnt, __ATOMIC_RELAXED,
                                         __HIP_MEMORY_SCOPE_AGENT) < target) {
                }
            }
            CFENCE();
            __syncthreads();
            CFENCE();   // block hoisting agent-scope loads above the gate

            // ---- async-stage split: issue ALL 16 sc1 loads, then
            //      write/compute half0 while half1 is still in flight ----
            const ull* hsrc = (const ull*)(hbuf + (size_t)((t - 1) & 1) * BB * HH);
            ull hr[16];
#pragma unroll
            for (int j = 0; j < 8; ++j)
                hr[j] = __hip_atomic_load(hsrc + (size_t)(b0 + j) * 512 + tid,
                                          __ATOMIC_RELAXED, __HIP_MEMORY_SCOPE_AGENT);
#pragma unroll
            for (int j = 0; j < 8; ++j)
                hr[8 + j] = __hip_atomic_load(hsrc + (size_t)(b0 + j) * 512 + 256 + tid,
                                              __ATOMIC_RELAXED, __HIP_MEMORY_SCOPE_AGENT);
#pragma unroll
            for (int j = 0; j < 8; ++j)
                *(ull*)&hs[j][tid * 2] = hr[j];
            __syncthreads();
            FMA_HALF(0)
#pragma unroll
            for (int j = 0; j < 8; ++j)
                *(ull*)&hs[j][512 + tid * 2] = hr[8 + j];
            __syncthreads();
            FMA_HALF(1)
        }

        // ---- folding in-wave reduce over kq ----
        int s = 64;
#pragma unroll
        for (int m = 1; m <= 32; m <<= 1) {
            const int hs_ = s >> 1;
            const bool hi = (lane & m) != 0;
#pragma unroll
            for (int i = 0; i < hs_; ++i) {
                float lo = a[i], hg = a[i + hs_];
                a[i]       = hi ? hg : lo;
                a[i + hs_] = hi ? lo : hg;
            }
#pragma unroll
            for (int i = 0; i < hs_; ++i) a[i] += __shfl_xor(a[i + hs_], m, 64);
            s = hs_;
        }

        red[wv][lane] = a[0];
        __syncthreads();

        // ---- epilogue: finalize, write out (plain), linearize into hout ----
        if (tid < 128) {
            const int l = tid & 63;
            const int nss = tid >> 6;
            float v = red[nss * 2][l] + red[nss * 2 + 1][l];
            float hv = tanhf(v + xp);
            out[xp_base + (size_t)t * HH] = hv;  // plain (write-only in-kernel)
            hout[eb][ec] = hv;
        }
        __syncthreads();

        // ---- coalesced h publish: 64 contiguous 8B sc1 stores ----
        if (tid < 64) {
            const int r  = tid >> 3;
            const int c2 = tid & 7;
            ull u = *(const ull*)&hout[r][c2 * 2];
            __hip_atomic_store(
                (ull*)(hbuf + (size_t)(t & 1) * BB * HH) +
                    (size_t)(b0 + r) * 512 + (n0 >> 1) + c2,
                u, __ATOMIC_RELAXED, __HIP_MEMORY_SCOPE_AGENT);
        }

        // ---- barrier drains vmcnt(0) (sc1 stores ACKed at MALL), then
        //      RELAXED aggregated counter add; fences pin store/add order ----
        CFENCE();
        __syncthreads();
        CFENCE();   // block sinking publish stores below / hoisting add above
        if (tid == 0)
            __hip_atomic_fetch_add(cnt, 1u, __ATOMIC_RELAXED,
                                   __HIP_MEMORY_SCOPE_AGENT);
    }
}

// ---------------- fallback path (tiny ws): multi-launch steps ----------------
__global__ __launch_bounds__(256) void h0wh(const float* __restrict__ Wh,
                                            const float* __restrict__ h0,
                                            float* __restrict__ c) {
    const int g = blockIdx.x;
    const int n = threadIdx.x * 4;
    float4 a = {0.f, 0.f, 0.f, 0.f};
    for (int kk = 0; kk < 16; ++kk) {
        int k = g * 16 + kk;
        float hv = h0[k];
        float4 w = *(const float4*)(Wh + (size_t)k * HH + n);
        a.x += hv * w.x; a.y += hv * w.y; a.z += hv * w.z; a.w += hv * w.w;
    }
    atomicAdd(&c[n + 0], a.x);
    atomicAdd(&c[n + 1], a.y);
    atomicAdd(&c[n + 2], a.z);
    atomicAdd(&c[n + 3], a.w);
}

__global__ __launch_bounds__(256) void t0_kernel(float* __restrict__ out,
                                                 const float* __restrict__ c) {
    const int idx = blockIdx.x * 256 + threadIdx.x;
    const int b = idx >> 10;
    const int n = idx & 1023;
    const size_t p = (size_t)b * SS * HH + n;
    out[p] = tanhf(out[p] + c[n]);
}

__global__ __launch_bounds__(256) void rnn_step(const float* __restrict__ Wh,
                                                float* __restrict__ out, int t) {
    __shared__ float hsl[8][1028];
    __shared__ float ps[256];
    const int tid = threadIdx.x;
    const int n0 = blockIdx.x * 16;
    const int b0 = blockIdx.y * 8;
    for (int i = tid; i < 8 * 256; i += 256) {
        int r = i >> 8;
        int c = (i & 255) << 2;
        *(float4*)&hsl[r][c] =
            *(const float4*)(out + ((size_t)(b0 + r) * SS + (t - 1)) * HH + c);
    }
    __syncthreads();
    const int nl = tid & 15;
    const int bl = (tid >> 4) & 7;
    const int half_ = tid >> 7;
    const int n = n0 + nl;
    float acc = 0.f;
    const float* hrow = &hsl[bl][half_ * 512];
    const float* wcol = Wh + (size_t)(half_ * 512) * HH + n;
#pragma unroll 4
    for (int k = 0; k < 512; k += 4) {
        float4 h4 = *(const float4*)(hrow + k);
        acc += h4.x * wcol[(size_t)(k + 0) * HH];
        acc += h4.y * wcol[(size_t)(k + 1) * HH];
        acc += h4.z * wcol[(size_t)(k + 2) * HH];
        acc += h4.w * wcol[(size_t)(k + 3) * HH];
    }
    ps[tid] = acc;
    __syncthreads();
    if (tid < 128) {
        const size_t obase = ((size_t)(b0 + bl) * SS + t) * HH + n;
        out[obase] = tanhf(out[obase] + ps[tid] + ps[tid + 128]);
    }
}

extern "C" void kernel_launch(void* const* d_in, const int* in_sizes, int n_in,
                              void* d_out, int out_size, void* d_ws, size_t ws_size,
                              hipStream_t stream) {
    const float* x    = (const float*)d_in[0];
    const float* Wx   = (const float*)d_in[1];
    const float* Wh   = (const float*)d_in[2];
    const float* bias = (const float*)d_in[3];
    const float* h0   = (const float*)d_in[4];
    float* out = (float*)d_out;
    float* ws  = (float*)d_ws;

    // Phase 1: Xp = x@Wx + b -> d_out
    xw_gemm<<<dim3(8, 256), 256, 0, stream>>>(x, Wx, bias, out);

    // ws layout: [0..255] counters (uint) | [256..] hbuf 2*32*1024 f | WhT 1024^2 f
    const size_t need_persist = (size_t)(256 + 2 * BB * HH) * sizeof(float);
    const size_t need_wht     = need_persist + (size_t)HH * HH * sizeof(float);

    if (ws_size >= need_persist) {
        unsigned int* flags = (unsigned int*)ws;
        float* hbuf = ws + 256;
        hipMemsetAsync(flags, 0, 1024, stream);

        const float* WhT = nullptr;
        if (ws_size >= need_wht) {
            float* whtp = ws + 256 + 2 * BB * HH;
            transpose_wh<<<dim3(32, 32), 256, 0, stream>>>(Wh, whtp);
            WhT = whtp;
        }

        void* kargs[] = {(void*)&Wh, (void*)&WhT, (void*)&h0, (void*)&out,
                         (void*)&flags, (void*)&hbuf};
        hipError_t rc = hipLaunchCooperativeKernel((const void*)rnn_persist,
                                                   dim3(WGN), dim3(256), kargs, 0,
                                                   stream);
        if (rc != hipSuccess) {
            rnn_persist<<<dim3(WGN), dim3(256), 0, stream>>>(Wh, WhT, h0, out,
                                                             flags, hbuf);
        }
    } else {
        // emergency fallback: multi-launch (correct, slow)
        float* cvec = ws;  // 1024 floats
        hipMemsetAsync(cvec, 0, HH * sizeof(float), stream);
        h0wh<<<64, 256, 0, stream>>>(Wh, h0, cvec);
        t0_kernel<<<BB * HH / 256, 256, 0, stream>>>(out, cvec);
        for (int t = 1; t < SS; ++t)
            rnn_step<<<dim3(64, 4), 256, 0, stream>>>(Wh, out, t);
    }
}